// Round 2
// baseline (426.715 us; speedup 1.0000x reference)
//
#include <hip/hip_runtime.h>
#include <math.h>

#define Nn 32
#define Cc 64
#define Tt 128
#define Vv 25
#define Kk 204800   // C*T*V
#define Hh 256
#define Ee 4
#define KC 256
#define NBLK_A 800  // Kk / KC

__device__ __forceinline__ float elu1(float v) { return v > 0.0f ? v : expm1f(v); }

// ---------------- Kernel A: split-K  partials[b][n][h] = sum_{k in chunk b} x[n,k]*W0[k,h]
// 800 blocks x 256 thr. LDS 32KB -> 3 blocks/CU. Thread tile: 4n x 8h.
__global__ __launch_bounds__(256) void kA(const float* __restrict__ x,
                                          const float* __restrict__ W0,
                                          float* __restrict__ partials) {
  __shared__ float xs[Nn][KC];   // 32 KB
  const int tid = threadIdx.x;
  const int b = blockIdx.x;
  const int k0 = b * KC;

  // stage x[0:32, k0:k0+256): 2048 float4 loads, 8 per thread
  #pragma unroll
  for (int j = tid; j < Nn * (KC / 4); j += 256) {
    int n = j >> 6;            // KC/4 = 64 per row
    int c4 = j & 63;
    float4 v = *(const float4*)(x + (size_t)n * Kk + k0 + c4 * 4);
    *(float4*)&xs[n][c4 * 4] = v;
  }
  __syncthreads();

  const int hg = tid & 31;   // h0 = hg*8
  const int np = tid >> 5;   // n0 = np*4
  const int h0 = hg * 8;
  const int n0 = np * 4;
  const float* W0p = W0 + (size_t)k0 * Hh + h0;

  float acc[4][8];
  #pragma unroll
  for (int i = 0; i < 4; ++i)
    #pragma unroll
    for (int c = 0; c < 8; ++c) acc[i][c] = 0.0f;

  for (int kk = 0; kk < KC; kk += 4) {
    float4 xv[4];
    #pragma unroll
    for (int i = 0; i < 4; ++i)
      xv[i] = *(const float4*)&xs[n0 + i][kk];   // wave-uniform addr -> broadcast
    #pragma unroll
    for (int u = 0; u < 4; ++u) {
      const float* wp = W0p + (size_t)(kk + u) * Hh;
      float4 wa = *(const float4*)(wp);
      float4 wb = *(const float4*)(wp + 4);
      #pragma unroll
      for (int i = 0; i < 4; ++i) {
        float xu = (u == 0) ? xv[i].x : (u == 1) ? xv[i].y : (u == 2) ? xv[i].z : xv[i].w;
        acc[i][0] = fmaf(xu, wa.x, acc[i][0]);
        acc[i][1] = fmaf(xu, wa.y, acc[i][1]);
        acc[i][2] = fmaf(xu, wa.z, acc[i][2]);
        acc[i][3] = fmaf(xu, wa.w, acc[i][3]);
        acc[i][4] = fmaf(xu, wb.x, acc[i][4]);
        acc[i][5] = fmaf(xu, wb.y, acc[i][5]);
        acc[i][6] = fmaf(xu, wb.z, acc[i][6]);
        acc[i][7] = fmaf(xu, wb.w, acc[i][7]);
      }
    }
  }
  #pragma unroll
  for (int i = 0; i < 4; ++i) {
    float* pp = partials + ((size_t)(b * Nn + n0 + i) << 8) + h0;
    *(float4*)(pp)     = make_float4(acc[i][0], acc[i][1], acc[i][2], acc[i][3]);
    *(float4*)(pp + 4) = make_float4(acc[i][4], acc[i][5], acc[i][6], acc[i][7]);
  }
}

// ---------------- Kernel B1: reduce 800 partials, + b0, ELU  -> hb[n][h]
__global__ __launch_bounds__(256) void kB1(const float* __restrict__ partials,
                                           const float* __restrict__ b0,
                                           float* __restrict__ hb) {
  const int n  = blockIdx.x >> 3;
  const int hc = blockIdx.x & 7;
  const int tid = threadIdx.x;
  const int hl = tid & 31;
  const int bsub = tid >> 5;     // 8 sub-reducers x 100 each
  const int h = hc * 32 + hl;
  float s = 0.0f;
  for (int j = 0; j < 100; ++j) {
    int b = bsub * 100 + j;
    s += partials[((size_t)(b * Nn + n) << 8) + h];
  }
  __shared__ float red[8][32];
  red[bsub][hl] = s;
  __syncthreads();
  if (tid < 32) {
    float tot = 0.0f;
    #pragma unroll
    for (int sI = 0; sI < 8; ++sI) tot += red[sI][tid];
    int hh = hc * 32 + tid;
    hb[n * Hh + hh] = elu1(tot + b0[hh]);
  }
}

// ---------------- Kernel B2: h2 = elu(hb@W1+b1); logits = h2@W2+b2; softmax -> wgt[n][e]
__global__ __launch_bounds__(256) void kB2(const float* __restrict__ hb,
                                           const float* __restrict__ W1,
                                           const float* __restrict__ b1,
                                           const float* __restrict__ W2,
                                           const float* __restrict__ b2,
                                           float* __restrict__ wgt) {
  const int n = blockIdx.x;
  const int tid = threadIdx.x;
  __shared__ float hbs[Hh];
  hbs[tid] = hb[n * Hh + tid];
  __syncthreads();
  float s = b1[tid];
  for (int j = 0; j < Hh; ++j) s = fmaf(hbs[j], W1[j * Hh + tid], s);
  float h2 = elu1(s);
  float le[Ee];
  #pragma unroll
  for (int e = 0; e < Ee; ++e) le[e] = h2 * W2[tid * Ee + e];
  __shared__ float red[Ee][4];
  const int lane = tid & 63;
  const int wid  = tid >> 6;
  #pragma unroll
  for (int e = 0; e < Ee; ++e) {
    float v = le[e];
    for (int off = 32; off > 0; off >>= 1) v += __shfl_down(v, off, 64);
    if (lane == 0) red[e][wid] = v;
  }
  __syncthreads();
  if (tid == 0) {
    float lg[Ee];
    float m = -1e30f;
    #pragma unroll
    for (int e = 0; e < Ee; ++e) {
      lg[e] = red[e][0] + red[e][1] + red[e][2] + red[e][3] + b2[e];
      m = fmaxf(m, lg[e]);
    }
    float den = 0.0f;
    #pragma unroll
    for (int e = 0; e < Ee; ++e) { lg[e] = expf(lg[e] - m); den += lg[e]; }
    float inv = 1.0f / den;
    #pragma unroll
    for (int e = 0; e < Ee; ++e) wgt[n * Ee + e] = lg[e] * inv;
  }
}

// ---------------- Kernel C: per (n,t): AS[v][w] = sum_e wgt[n][e]*A[e][t][v][w];
//                  out[n][c][t][w] = sum_v x[n][c][t][v] * AS[v][w]
// 2048 blocks, each handles 2 t. Register tile 4c x 4w; both LDS operands read as b128.
#define ASW 28   // padded AS row (25 -> 28, 16B-aligned rows)
#define XTS 68   // padded xT row (64 -> 68, keeps float4 alignment)
__global__ __launch_bounds__(256) void kC(const float* __restrict__ x,
                                          const float* __restrict__ A,
                                          const float* __restrict__ wgt,
                                          float* __restrict__ out) {
  const int blk = blockIdx.x;
  const int n  = blk >> 6;       // 32 n
  const int tp = blk & 63;       // 64 t-pairs
  const int tid = threadIdx.x;
  const int tsub = tid >> 7;     // which t of the pair
  const int tl = tid & 127;
  const int t = tp * 2 + tsub;

  __shared__ float AS[2][Vv][ASW];   // 5.6 KB
  __shared__ float xT[2][Vv][XTS];   // 13.6 KB

  float wv[Ee];
  #pragma unroll
  for (int e = 0; e < Ee; ++e) wv[e] = wgt[n * Ee + e];

  // build AS (padded cols zeroed)
  for (int idx = tl; idx < Vv * ASW; idx += 128) {
    int v = idx / ASW;
    int w = idx - v * ASW;
    float s = 0.0f;
    if (w < Vv) {
      #pragma unroll
      for (int e = 0; e < Ee; ++e)
        s = fmaf(wv[e], A[((size_t)(e * Tt + t) * Vv + v) * Vv + w], s);
    }
    AS[tsub][v][w] = s;
  }
  // stage x transposed: xT[v][c] = x[n][c][t][v]
  const float* xb = x + (size_t)n * (Cc * Tt * Vv) + (size_t)t * Vv;
  for (int idx = tl; idx < Cc * Vv; idx += 128) {
    int c = idx / Vv;
    int v = idx - c * Vv;
    xT[tsub][v][c] = xb[(size_t)c * (Tt * Vv) + v];
  }
  __syncthreads();

  const int ct = tl & 15;        // c0 = ct*4
  const int wq = tl >> 4;        // 0..7, active if <7
  if (wq < 7) {
    const int c0 = ct * 4;
    const int w0 = wq * 4;
    float acc[4][4];
    #pragma unroll
    for (int i = 0; i < 4; ++i)
      #pragma unroll
      for (int j = 0; j < 4; ++j) acc[i][j] = 0.0f;
    #pragma unroll 5
    for (int v = 0; v < Vv; ++v) {
      float4 a4 = *(const float4*)&AS[tsub][v][w0];
      float4 x4 = *(const float4*)&xT[tsub][v][c0];
      const float xr[4] = {x4.x, x4.y, x4.z, x4.w};
      const float ar[4] = {a4.x, a4.y, a4.z, a4.w};
      #pragma unroll
      for (int i = 0; i < 4; ++i)
        #pragma unroll
        for (int j = 0; j < 4; ++j)
          acc[i][j] = fmaf(xr[i], ar[j], acc[i][j]);
    }
    #pragma unroll
    for (int i = 0; i < 4; ++i) {
      int c = c0 + i;
      float* ob = out + ((size_t)(n * Cc + c) * Tt + t) * Vv;
      #pragma unroll
      for (int j = 0; j < 4; ++j) {
        int w = w0 + j;
        if (w < Vv) ob[w] = acc[i][j];
      }
    }
  }
}

extern "C" void kernel_launch(void* const* d_in, const int* in_sizes, int n_in,
                              void* d_out, int out_size, void* d_ws, size_t ws_size,
                              hipStream_t stream) {
  const float* x  = (const float*)d_in[0];
  const float* W0 = (const float*)d_in[1];
  const float* b0 = (const float*)d_in[2];
  const float* W1 = (const float*)d_in[3];
  const float* b1 = (const float*)d_in[4];
  const float* W2 = (const float*)d_in[5];
  const float* b2 = (const float*)d_in[6];
  const float* A  = (const float*)d_in[7];
  float* out = (float*)d_out;

  float* partials = (float*)d_ws;                          // 800*32*256 floats = 26.2 MB
  float* hb  = partials + (size_t)NBLK_A * Nn * Hh;        // 8192 floats
  float* wgt = hb + Nn * Hh;                               // 128 floats

  kA <<<NBLK_A,  256, 0, stream>>>(x, W0, partials);
  kB1<<<256,     256, 0, stream>>>(partials, b0, hb);
  kB2<<<Nn,      256, 0, stream>>>(hb, W1, b1, W2, b2, wgt);
  kC <<<Nn * 64, 256, 0, stream>>>(x, A, wgt, out);
}

// Round 3
// 379.149 us; speedup vs baseline: 1.1255x; 1.1255x over previous
//
#include <hip/hip_runtime.h>
#include <math.h>

#define Nn 32
#define Cc 64
#define Tt 128
#define Vv 25
#define Kk 204800   // C*T*V
#define Hh 256
#define Ee 4
#define KC 256
#define KB 16              // W0 rows per async buffer (16 KB)
#define NSTEP (KC / KB)    // 16
#define NBLK_A 800         // Kk / KC

__device__ __forceinline__ float elu1(float v) { return v > 0.0f ? v : expm1f(v); }

typedef const __attribute__((address_space(1))) void* gvp;
typedef __attribute__((address_space(3))) void* lvp;
// async DMA global->LDS, 16B per lane, lands at ldsbase + lane*16
__device__ __forceinline__ void gl_lds16(const void* g, void* l) {
  __builtin_amdgcn_global_load_lds((gvp)g, (lvp)l, 16, 0, 0);
}

// ---------------- Kernel A: split-K  partials[b][n][h] = sum_{k in chunk b} x[n,k]*W0[k,h]
// 800 blocks x 256 thr. LDS: xs 32KB + W0 double-buffer 32KB -> 2 blocks/CU.
// W0 streamed via async global_load_lds (no VGPR round-trip, deep in-flight queue).
__global__ __launch_bounds__(256) void kA(const float* __restrict__ x,
                                          const float* __restrict__ W0,
                                          float* __restrict__ partials) {
  __shared__ float xs[Nn][KC];        // 32 KB
  __shared__ float wbuf[2][KB][Hh];   // 32 KB
  const int tid  = threadIdx.x;
  const int lane = tid & 63;
  const int wv   = tid >> 6;
  const int b  = blockIdx.x;
  const int k0 = b * KC;

  // async-stage x[0:32, k0:k0+256): 32 rows x 1KB, one DMA per row
  for (int r = wv; r < Nn; r += 4)
    gl_lds16(x + (size_t)r * Kk + k0 + lane * 4, &xs[r][0]);
  // prefetch W0 buffer 0 (rows 0..15)
  for (int r = wv; r < KB; r += 4)
    gl_lds16(W0 + (size_t)(k0 + r) * Hh + lane * 4, &wbuf[0][r][0]);
  __syncthreads();

  const int hg = tid & 31;   // h0 = hg*8
  const int np = tid >> 5;   // n0 = np*4
  const int h0 = hg * 8;
  const int n0 = np * 4;

  float acc[4][8];
  #pragma unroll
  for (int i = 0; i < 4; ++i)
    #pragma unroll
    for (int c = 0; c < 8; ++c) acc[i][c] = 0.0f;

  for (int step = 0; step < NSTEP; ++step) {
    const int cur = step & 1;
    // issue async prefetch of next buffer (fire-and-forget)
    if (step + 1 < NSTEP) {
      const int kb = (step + 1) * KB;
      for (int r = wv; r < KB; r += 4)
        gl_lds16(W0 + (size_t)(k0 + kb + r) * Hh + lane * 4, &wbuf[cur ^ 1][r][0]);
    }
    const int kbase = step * KB;
    #pragma unroll
    for (int kk = 0; kk < KB; kk += 4) {
      float4 xv[4];
      #pragma unroll
      for (int i = 0; i < 4; ++i)
        xv[i] = *(const float4*)&xs[n0 + i][kbase + kk];  // 2-way broadcast: free
      #pragma unroll
      for (int u = 0; u < 4; ++u) {
        const float* wp = &wbuf[cur][kk + u][h0];
        float4 wa = *(const float4*)(wp);
        float4 wb = *(const float4*)(wp + 4);
        #pragma unroll
        for (int i = 0; i < 4; ++i) {
          float xu = (u == 0) ? xv[i].x : (u == 1) ? xv[i].y : (u == 2) ? xv[i].z : xv[i].w;
          acc[i][0] = fmaf(xu, wa.x, acc[i][0]);
          acc[i][1] = fmaf(xu, wa.y, acc[i][1]);
          acc[i][2] = fmaf(xu, wa.z, acc[i][2]);
          acc[i][3] = fmaf(xu, wa.w, acc[i][3]);
          acc[i][4] = fmaf(xu, wb.x, acc[i][4]);
          acc[i][5] = fmaf(xu, wb.y, acc[i][5]);
          acc[i][6] = fmaf(xu, wb.z, acc[i][6]);
          acc[i][7] = fmaf(xu, wb.w, acc[i][7]);
        }
      }
    }
    __syncthreads();   // buffer handoff (also drains prefetch DMAs)
  }

  #pragma unroll
  for (int i = 0; i < 4; ++i) {
    float* pp = partials + ((size_t)(b * Nn + n0 + i) << 8) + h0;
    *(float4*)(pp)     = make_float4(acc[i][0], acc[i][1], acc[i][2], acc[i][3]);
    *(float4*)(pp + 4) = make_float4(acc[i][4], acc[i][5], acc[i][6], acc[i][7]);
  }
}

// ---------------- Kernel B1: reduce 800 partials, + b0, ELU  -> hb[n][h]
__global__ __launch_bounds__(256) void kB1(const float* __restrict__ partials,
                                           const float* __restrict__ b0,
                                           float* __restrict__ hb) {
  const int n  = blockIdx.x >> 3;
  const int hc = blockIdx.x & 7;
  const int tid = threadIdx.x;
  const int hl = tid & 31;
  const int bsub = tid >> 5;     // 8 sub-reducers x 100 each
  const int h = hc * 32 + hl;
  float s = 0.0f;
  for (int j = 0; j < 100; ++j) {
    int b = bsub * 100 + j;
    s += partials[((size_t)(b * Nn + n) << 8) + h];
  }
  __shared__ float red[8][32];
  red[bsub][hl] = s;
  __syncthreads();
  if (tid < 32) {
    float tot = 0.0f;
    #pragma unroll
    for (int sI = 0; sI < 8; ++sI) tot += red[sI][tid];
    int hh = hc * 32 + tid;
    hb[n * Hh + hh] = elu1(tot + b0[hh]);
  }
}

// ---------------- Kernel B2: h2 = elu(hb@W1+b1); logits = h2@W2+b2; softmax -> wgt[n][e]
__global__ __launch_bounds__(256) void kB2(const float* __restrict__ hb,
                                           const float* __restrict__ W1,
                                           const float* __restrict__ b1,
                                           const float* __restrict__ W2,
                                           const float* __restrict__ b2,
                                           float* __restrict__ wgt) {
  const int n = blockIdx.x;
  const int tid = threadIdx.x;
  __shared__ float hbs[Hh];
  hbs[tid] = hb[n * Hh + tid];
  __syncthreads();
  float s = b1[tid];
  for (int j = 0; j < Hh; ++j) s = fmaf(hbs[j], W1[j * Hh + tid], s);
  float h2 = elu1(s);
  float le[Ee];
  #pragma unroll
  for (int e = 0; e < Ee; ++e) le[e] = h2 * W2[tid * Ee + e];
  __shared__ float red[Ee][4];
  const int lane = tid & 63;
  const int wid  = tid >> 6;
  #pragma unroll
  for (int e = 0; e < Ee; ++e) {
    float v = le[e];
    for (int off = 32; off > 0; off >>= 1) v += __shfl_down(v, off, 64);
    if (lane == 0) red[e][wid] = v;
  }
  __syncthreads();
  if (tid == 0) {
    float lg[Ee];
    float m = -1e30f;
    #pragma unroll
    for (int e = 0; e < Ee; ++e) {
      lg[e] = red[e][0] + red[e][1] + red[e][2] + red[e][3] + b2[e];
      m = fmaxf(m, lg[e]);
    }
    float den = 0.0f;
    #pragma unroll
    for (int e = 0; e < Ee; ++e) { lg[e] = expf(lg[e] - m); den += lg[e]; }
    float inv = 1.0f / den;
    #pragma unroll
    for (int e = 0; e < Ee; ++e) wgt[n * Ee + e] = lg[e] * inv;
  }
}

// ---------------- Kernel C: per (n,t): AS[v][w] = sum_e wgt[n][e]*A[e][t][v][w];
//                  out[n][c][t][w] = sum_v x[n][c][t][v] * AS[v][w]
#define ASW 28   // padded AS row
#define XTS 68   // padded xT row
__global__ __launch_bounds__(256) void kC(const float* __restrict__ x,
                                          const float* __restrict__ A,
                                          const float* __restrict__ wgt,
                                          float* __restrict__ out) {
  const int blk = blockIdx.x;
  const int n  = blk >> 6;       // 32 n
  const int tp = blk & 63;       // 64 t-pairs
  const int tid = threadIdx.x;
  const int tsub = tid >> 7;     // which t of the pair
  const int tl = tid & 127;
  const int t = tp * 2 + tsub;

  __shared__ float AS[2][Vv][ASW];
  __shared__ float xT[2][Vv][XTS];

  float wv[Ee];
  #pragma unroll
  for (int e = 0; e < Ee; ++e) wv[e] = wgt[n * Ee + e];

  for (int idx = tl; idx < Vv * ASW; idx += 128) {
    int v = idx / ASW;
    int w = idx - v * ASW;
    float s = 0.0f;
    if (w < Vv) {
      #pragma unroll
      for (int e = 0; e < Ee; ++e)
        s = fmaf(wv[e], A[((size_t)(e * Tt + t) * Vv + v) * Vv + w], s);
    }
    AS[tsub][v][w] = s;
  }
  const float* xb = x + (size_t)n * (Cc * Tt * Vv) + (size_t)t * Vv;
  for (int idx = tl; idx < Cc * Vv; idx += 128) {
    int c = idx / Vv;
    int v = idx - c * Vv;
    xT[tsub][v][c] = xb[(size_t)c * (Tt * Vv) + v];
  }
  __syncthreads();

  const int ct = tl & 15;        // c0 = ct*4
  const int wq = tl >> 4;        // 0..7, active if <7
  if (wq < 7) {
    const int c0 = ct * 4;
    const int w0 = wq * 4;
    float acc[4][4];
    #pragma unroll
    for (int i = 0; i < 4; ++i)
      #pragma unroll
      for (int j = 0; j < 4; ++j) acc[i][j] = 0.0f;
    #pragma unroll 5
    for (int v = 0; v < Vv; ++v) {
      float4 a4 = *(const float4*)&AS[tsub][v][w0];
      float4 x4 = *(const float4*)&xT[tsub][v][c0];
      const float xr[4] = {x4.x, x4.y, x4.z, x4.w};
      const float ar[4] = {a4.x, a4.y, a4.z, a4.w};
      #pragma unroll
      for (int i = 0; i < 4; ++i)
        #pragma unroll
        for (int j = 0; j < 4; ++j)
          acc[i][j] = fmaf(xr[i], ar[j], acc[i][j]);
    }
    #pragma unroll
    for (int i = 0; i < 4; ++i) {
      int c = c0 + i;
      float* ob = out + ((size_t)(n * Cc + c) * Tt + t) * Vv;
      #pragma unroll
      for (int j = 0; j < 4; ++j) {
        int w = w0 + j;
        if (w < Vv) ob[w] = acc[i][j];
      }
    }
  }
}

extern "C" void kernel_launch(void* const* d_in, const int* in_sizes, int n_in,
                              void* d_out, int out_size, void* d_ws, size_t ws_size,
                              hipStream_t stream) {
  const float* x  = (const float*)d_in[0];
  const float* W0 = (const float*)d_in[1];
  const float* b0 = (const float*)d_in[2];
  const float* W1 = (const float*)d_in[3];
  const float* b1 = (const float*)d_in[4];
  const float* W2 = (const float*)d_in[5];
  const float* b2 = (const float*)d_in[6];
  const float* A  = (const float*)d_in[7];
  float* out = (float*)d_out;

  float* partials = (float*)d_ws;                          // 800*32*256 floats = 26.2 MB
  float* hb  = partials + (size_t)NBLK_A * Nn * Hh;        // 8192 floats
  float* wgt = hb + Nn * Hh;                               // 128 floats

  kA <<<NBLK_A,  256, 0, stream>>>(x, W0, partials);
  kB1<<<256,     256, 0, stream>>>(partials, b0, hb);
  kB2<<<Nn,      256, 0, stream>>>(hb, W1, b1, W2, b2, wgt);
  kC <<<Nn * 64, 256, 0, stream>>>(x, A, wgt, out);
}